// Round 15
// baseline (621.172 us; speedup 1.0000x reference)
//
#include <hip/hip_runtime.h>
#include <math.h>

constexpr int NCOLS   = 70;
constexpr int NH      = 64;
constexpr int EMB     = 128;
constexpr int DD      = 192;
constexpr int RES_HID = 512;
constexpr int PRED_HID= 320;

typedef _Float16 f16x8 __attribute__((ext_vector_type(8)));
typedef float    f32x4 __attribute__((ext_vector_type(4)));
#define MFMA16F(a,b,c) __builtin_amdgcn_mfma_f32_16x16x32_f16((a),(b),(c),0,0,0)

constexpr float LO_SCALE   = 4096.0f;
constexpr float LO_DESCALE = 1.0f/4096.0f;
constexpr float Z_SCALE    = 0.0625f;
constexpr float Z_DESCALE  = 16.0f;

__device__ __forceinline__ float leaky(float x){ return x > 0.f ? x : 0.01f*x; }

// ===================== CSR build for GCN aggregation ======================
__global__ void k_scanA(const int* __restrict__ cnt, int* __restrict__ bsum, int n){
  __shared__ int s;
  if (threadIdx.x == 0) s = 0;
  __syncthreads();
  int i = blockIdx.x*256 + threadIdx.x;
  int v = (i < n) ? cnt[i] : 0;
  #pragma unroll
  for (int o=32;o;o>>=1) v += __shfl_xor(v, o, 64);
  if ((threadIdx.x & 63) == 0) atomicAdd(&s, v);
  __syncthreads();
  if (threadIdx.x == 0) bsum[blockIdx.x] = s;
}
__global__ void k_scanB(int* bsum, int nb){
  __shared__ int s[256];
  __shared__ int carry;
  if (threadIdx.x == 0) carry = 0;
  __syncthreads();
  for (int start = 0; start < nb; start += 256){
    int i = start + threadIdx.x;
    int v = (i < nb) ? bsum[i] : 0;
    s[threadIdx.x] = v; __syncthreads();
    for (int o=1;o<256;o<<=1){
      int t = (threadIdx.x >= o) ? s[threadIdx.x-o] : 0;
      __syncthreads();
      s[threadIdx.x] += t; __syncthreads();
    }
    if (i < nb) bsum[i] = carry + s[threadIdx.x] - v;
    __syncthreads();
    if (threadIdx.x == 255) carry += s[255];
    __syncthreads();
  }
}
__global__ void k_scanC(const int* __restrict__ cnt, const int* __restrict__ bsum,
                        int* __restrict__ base, int* __restrict__ cursor,
                        float* __restrict__ dinv, int n, int E){
  __shared__ int s[256];
  int i = blockIdx.x*256 + threadIdx.x;
  int v = (i < n) ? cnt[i] : 0;
  s[threadIdx.x] = v; __syncthreads();
  for (int o=1;o<256;o<<=1){
    int t = (threadIdx.x >= o) ? s[threadIdx.x-o] : 0;
    __syncthreads();
    s[threadIdx.x] += t; __syncthreads();
  }
  if (i < n){
    int b = bsum[blockIdx.x] + s[threadIdx.x] - v;
    base[i] = b; cursor[i] = b;
    dinv[i] = rsqrtf((float)(v + 1));
  }
  if (i == n-1) base[n] = E;
}
__global__ void k_fill(const int* __restrict__ row, const int* __restrict__ col,
                       const float* __restrict__ dinv, int* __restrict__ cursor,
                       int2* __restrict__ ebin, int E){
  int e = blockIdx.x*256 + threadIdx.x;
  if (e < E){
    int r = row[e], c = col[e];
    int slot = atomicAdd(&cursor[c], 1);
    ebin[slot] = make_int2(r, __float_as_int(dinv[r]));
  }
}

// ===== merged weight prep + degree histogram (independent work, 1 launch) =
__device__ __forceinline__ void pack_one(const float* __restrict__ W,
                                         _Float16* __restrict__ Wh, _Float16* __restrict__ Wl,
                                         int K, int N, int local){
  int k = local / N, nn = local - k*N;
  float v = W[local];
  _Float16 h = (_Float16)v;
  float lo = (v - (float)h)*LO_SCALE;
  int kc = k >> 5, r = k & 31;
  int lane = (nn & 15) | ((r >> 3) << 4);
  int j = r & 7;
  size_t dst = ((size_t)((nn >> 4)*(K >> 5) + kc) << 9) + lane*8 + j;
  Wh[dst] = h;
  Wl[dst] = (_Float16)lo;
}
__global__ void k_wprep_hist(const float* res_w1, const float* res_w2, const float* p_w1,
                             const float* w_g0, const float* w_gcn1, const float* w_gcn2,
                             _Float16* wt1h, _Float16* wt1l, _Float16* wt2h, _Float16* wt2l,
                             _Float16* wph, _Float16* wpl, _Float16* wg0h, _Float16* wg0l,
                             _Float16* wg1h, _Float16* wg1l, _Float16* wg2h, _Float16* wg2l,
                             const int* __restrict__ col, int* __restrict__ cnt, int E)
{
  int idx = blockIdx.x*256 + threadIdx.x;
  constexpr int SZ = DD*RES_HID;
  constexpr int PZ = 2*DD*PRED_HID;
  constexpr int TOT = 4*SZ + PZ + NH*EMB + 2*EMB*EMB;
  if (idx < SZ)                 pack_one(res_w1,           wt1h,      wt1l,      DD, RES_HID, idx);
  else if (idx < 2*SZ)          pack_one(res_w1 + SZ,      wt1h + SZ, wt1l + SZ, DD, RES_HID, idx - SZ);
  else if (idx < 3*SZ)          pack_one(res_w2,           wt2h,      wt2l,      RES_HID, DD, idx - 2*SZ);
  else if (idx < 4*SZ)          pack_one(res_w2 + SZ,      wt2h + SZ, wt2l + SZ, RES_HID, DD, idx - 3*SZ);
  else if (idx < 4*SZ + PZ)     pack_one(p_w1,             wph,       wpl,       2*DD, PRED_HID, idx - 4*SZ);
  else if (idx < 4*SZ + PZ + NH*EMB)
                                pack_one(w_g0,             wg0h,      wg0l,      NH, EMB, idx - 4*SZ - PZ);
  else if (idx < 4*SZ + PZ + NH*EMB + EMB*EMB)
                                pack_one(w_gcn1,           wg1h,      wg1l,      EMB, EMB, idx - 4*SZ - PZ - NH*EMB);
  else if (idx < TOT)           pack_one(w_gcn2,           wg2h,      wg2l,      EMB, EMB, idx - 4*SZ - PZ - NH*EMB - EMB*EMB);
  else if (idx < TOT + E)       atomicAdd(&cnt[col[idx - TOT]], 1);
}

// ======= fused embed + first linear (r13-proven) ==========================
__global__ __launch_bounds__(256,3)
void k_embed_lin(const int* __restrict__ dx,
                 const _Float16* __restrict__ Wh, const _Float16* __restrict__ Wl,
                 const float* __restrict__ bias,
                 float* __restrict__ A, float* __restrict__ out, int n)
{
  constexpr int KS = 68;
  __shared__ __align__(16) _Float16 xh[32*KS];
  int i0 = blockIdx.x*32;
  for (int idx = threadIdx.x; idx < 32*NH; idx += 256){
    int t = idx >> 6, k = idx & 63;
    int i = i0 + t;
    float v = (i < n) ? (float)dx[(size_t)i*NCOLS + k] : 0.f;
    if (i < n) A[(size_t)i*DD + k] = v;
    xh[t*KS + k] = (_Float16)v;
  }
  __syncthreads();
  int wv = threadIdx.x >> 6, ln = threadIdx.x & 63;
  int cn = ln & 15, kg = ln >> 4;
  f16x8 A0h[2], A1h[2];
  #pragma unroll
  for (int kc=0;kc<2;kc++){
    int k0 = kc*32 + kg*8;
    A0h[kc] = *(const f16x8*)&xh[cn*KS + k0];
    A1h[kc] = *(const f16x8*)&xh[(16+cn)*KS + k0];
  }
  #pragma unroll
  for (int t=0;t<2;t++){
    int nt = wv*2 + t, n0 = nt*16;
    const _Float16* wbh = Wh + (((size_t)nt*2) << 9) + ln*8;
    const _Float16* wbl = Wl + (((size_t)nt*2) << 9) + ln*8;
    f32x4 acc0={0.f,0.f,0.f,0.f}, accL0={0.f,0.f,0.f,0.f};
    f32x4 acc1={0.f,0.f,0.f,0.f}, accL1={0.f,0.f,0.f,0.f};
    #pragma unroll
    for (int kc=0;kc<2;kc++){
      f16x8 bh = *(const f16x8*)(wbh + ((size_t)kc<<9));
      f16x8 bl = *(const f16x8*)(wbl + ((size_t)kc<<9));
      acc0  = MFMA16F(A0h[kc], bh, acc0);
      accL0 = MFMA16F(A0h[kc], bl, accL0);
      acc1  = MFMA16F(A1h[kc], bh, acc1);
      accL1 = MFMA16F(A1h[kc], bl, accL1);
    }
    float bb = bias[n0 + cn];
    #pragma unroll
    for (int r=0;r<4;r++){
      int ia = i0 + kg*4 + r, ib = ia + 16;
      float v0 = leaky(acc0[r] + accL0[r]*LO_DESCALE + bb);
      float v1 = leaky(acc1[r] + accL1[r]*LO_DESCALE + bb);
      if (ia < n) out[(size_t)ia*EMB + n0 + cn] = v0;
      if (ib < n) out[(size_t)ib*EMB + n0 + cn] = v1;
    }
  }
}

// ============ MFMA dense layer, J=128, LDS-staged A =======================
template<int KC>
__global__ __launch_bounds__(256,3)
void k_lin_mfma2(const float* __restrict__ X, int ldx,
                 const _Float16* __restrict__ Wh, const _Float16* __restrict__ Wl,
                 const float* __restrict__ bias,
                 float* __restrict__ out, int ldo, int ooff, int n, int act)
{
  constexpr int K  = KC*32;
  constexpr int KS = K + 4;
  __shared__ __align__(16) _Float16 xh[32*KS];
  __shared__ __align__(16) _Float16 xl[32*KS];
  int i0 = blockIdx.x*32;
  for (int idx = threadIdx.x; idx < 32*K; idx += 256){
    int t = idx / K, k = idx - t*K;
    int i = i0 + t;
    float v = (i < n) ? X[(size_t)i*ldx + k] : 0.f;
    _Float16 h = (_Float16)v;
    xh[t*KS + k] = h;
    xl[t*KS + k] = (_Float16)((v - (float)h)*LO_SCALE);
  }
  __syncthreads();
  int wv = threadIdx.x >> 6, ln = threadIdx.x & 63;
  int cn = ln & 15, kg = ln >> 4;
  f16x8 A0h[KC], A0l[KC], A1h[KC], A1l[KC];
  #pragma unroll
  for (int kc=0;kc<KC;kc++){
    int k0 = kc*32 + kg*8;
    A0h[kc] = *(const f16x8*)&xh[cn*KS + k0];
    A0l[kc] = *(const f16x8*)&xl[cn*KS + k0];
    A1h[kc] = *(const f16x8*)&xh[(16+cn)*KS + k0];
    A1l[kc] = *(const f16x8*)&xl[(16+cn)*KS + k0];
  }
  #pragma unroll
  for (int t=0;t<2;t++){
    int nt = wv*2 + t, n0 = nt*16;
    const _Float16* wbh = Wh + (((size_t)nt*KC) << 9) + ln*8;
    const _Float16* wbl = Wl + (((size_t)nt*KC) << 9) + ln*8;
    f32x4 acc0={0.f,0.f,0.f,0.f}, accL0={0.f,0.f,0.f,0.f};
    f32x4 acc1={0.f,0.f,0.f,0.f}, accL1={0.f,0.f,0.f,0.f};
    #pragma unroll
    for (int kc=0;kc<KC;kc++){
      f16x8 bh = *(const f16x8*)(wbh + ((size_t)kc<<9));
      f16x8 bl = *(const f16x8*)(wbl + ((size_t)kc<<9));
      acc0  = MFMA16F(A0h[kc], bh, acc0);
      accL0 = MFMA16F(A0l[kc], bh, accL0);
      accL0 = MFMA16F(A0h[kc], bl, accL0);
      acc1  = MFMA16F(A1h[kc], bh, acc1);
      accL1 = MFMA16F(A1l[kc], bh, accL1);
      accL1 = MFMA16F(A1h[kc], bl, accL1);
    }
    float bb = bias ? bias[n0 + cn] : 0.f;
    #pragma unroll
    for (int r=0;r<4;r++){
      int ia = i0 + kg*4 + r, ib = ia + 16;
      float v0 = acc0[r] + accL0[r]*LO_DESCALE + bb;
      float v1 = acc1[r] + accL1[r]*LO_DESCALE + bb;
      if (act){ v0 = leaky(v0); v1 = leaky(v1); }
      if (ia < n) out[(size_t)ia*ldo + ooff + n0 + cn] = v0;
      if (ib < n) out[(size_t)ib*ldo + ooff + n0 + cn] = v1;
    }
  }
}

// ========== GCN gather v3: 2 waves/node, 4 edges in flight ================
__global__ void k_gather(const float* __restrict__ h, const float* __restrict__ dinv,
                         const int* __restrict__ base, const int2* __restrict__ ebin,
                         const float* __restrict__ bias, float* __restrict__ out,
                         int ldo, int ooff, int n)
{
  __shared__ float4 red[2][4][32];
  int slot = threadIdx.x >> 7;           // 0/1: node slot within block
  int node = blockIdx.x*2 + slot;
  int t128 = threadIdx.x & 127;
  int g   = t128 >> 5;                   // edge group 0..3
  int l32 = t128 & 31;
  float4 acc = {0.f,0.f,0.f,0.f};
  if (node < n){
    int b0 = base[node], b1 = base[node+1];
    for (int e = b0 + g; e < b1; e += 4){
      int2 ee = ebin[e];
      float4 hv = ((const float4*)(h + (size_t)ee.x*EMB))[l32];
      float dd = __int_as_float(ee.y);
      acc.x = fmaf(hv.x, dd, acc.x);
      acc.y = fmaf(hv.y, dd, acc.y);
      acc.z = fmaf(hv.z, dd, acc.z);
      acc.w = fmaf(hv.w, dd, acc.w);
    }
  }
  red[slot][g][l32] = acc;
  __syncthreads();
  if (node < n && g == 0){
    float4 a0 = red[slot][0][l32], a1 = red[slot][1][l32];
    float4 a2 = red[slot][2][l32], a3 = red[slot][3][l32];
    float dc = dinv[node];
    float4 hc = ((const float4*)(h + (size_t)node*EMB))[l32];
    float4 bv = ((const float4*)bias)[l32];
    float4 res;
    res.x = leaky((a0.x+a1.x+a2.x+a3.x + hc.x*dc)*dc + bv.x);
    res.y = leaky((a0.y+a1.y+a2.y+a3.y + hc.y*dc)*dc + bv.y);
    res.z = leaky((a0.z+a1.z+a2.z+a3.z + hc.z*dc)*dc + bv.z);
    res.w = leaky((a0.w+a1.w+a2.w+a3.w + hc.w*dc)*dc + bv.w);
    *(float4*)(out + (size_t)node*ldo + ooff + 4*l32) = res;
  }
}

// ===================== fused MFMA residual bottleneck (r10/r13 proven) ====
constexpr int XS = 196;
constexpr int HS = 516;

__global__ __launch_bounds__(256,2)
void k_resblock_mfma(const float* __restrict__ X,
                     const _Float16* __restrict__ W1h, const _Float16* __restrict__ W1l,
                     const float* __restrict__ b1,
                     const _Float16* __restrict__ W2h, const _Float16* __restrict__ W2l,
                     const float* __restrict__ b2,
                     float* __restrict__ out, int n)
{
  __shared__ __align__(16) _Float16 xh[32*XS];
  __shared__ __align__(16) _Float16 xl[32*XS];
  __shared__ __align__(16) _Float16 hh[32*HS];
  int i0 = blockIdx.x*32;
  for (int idx = threadIdx.x; idx < 32*DD; idx += 256){
    int t = idx / DD, k = idx - t*DD;
    int i = i0 + t;
    float v = (i < n) ? X[(size_t)i*DD + k] : 0.f;
    _Float16 h = (_Float16)v;
    xh[t*XS + k] = h;
    xl[t*XS + k] = (_Float16)((v - (float)h)*LO_SCALE);
  }
  __syncthreads();
  int wv = threadIdx.x >> 6, ln = threadIdx.x & 63;
  int cn = ln & 15, kg = ln >> 4;

  {
    f16x8 A0h[6], A0l[6], A1h[6], A1l[6];
    #pragma unroll
    for (int kc=0;kc<6;kc++){
      int k0 = kc*32 + kg*8;
      A0h[kc] = *(const f16x8*)&xh[cn*XS + k0];
      A0l[kc] = *(const f16x8*)&xl[cn*XS + k0];
      A1h[kc] = *(const f16x8*)&xh[(16+cn)*XS + k0];
      A1l[kc] = *(const f16x8*)&xl[(16+cn)*XS + k0];
    }
    float bias1[8];
    #pragma unroll
    for (int ct=0;ct<8;ct++) bias1[ct] = b1[(wv*8+ct)*16 + cn];
    const _Float16* pbh = W1h + ((size_t)(wv*8)*6 << 9) + ln*8;
    const _Float16* pbl = W1l + ((size_t)(wv*8)*6 << 9) + ln*8;
    f16x8 Bh[6], Bl[6];
    #pragma unroll
    for (int kc=0;kc<6;kc++){
      Bh[kc] = *(const f16x8*)(pbh + ((size_t)kc<<9));
      Bl[kc] = *(const f16x8*)(pbl + ((size_t)kc<<9));
    }
    #pragma unroll 1
    for (int ct = 0; ct < 8; ct++){
      f16x8 Bh2[6], Bl2[6];
      if (ct < 7){
        const _Float16* nh = pbh + ((size_t)((ct+1)*6) << 9);
        const _Float16* nl = pbl + ((size_t)((ct+1)*6) << 9);
        #pragma unroll
        for (int kc=0;kc<6;kc++){
          Bh2[kc] = *(const f16x8*)(nh + ((size_t)kc<<9));
          Bl2[kc] = *(const f16x8*)(nl + ((size_t)kc<<9));
        }
      }
      f32x4 acc0={0.f,0.f,0.f,0.f}, accL0={0.f,0.f,0.f,0.f};
      f32x4 acc1={0.f,0.f,0.f,0.f}, accL1={0.f,0.f,0.f,0.f};
      #pragma unroll
      for (int kc=0;kc<6;kc++){
        acc0  = MFMA16F(A0h[kc], Bh[kc], acc0);
        accL0 = MFMA16F(A0l[kc], Bh[kc], accL0);
        accL0 = MFMA16F(A0h[kc], Bl[kc], accL0);
        acc1  = MFMA16F(A1h[kc], Bh[kc], acc1);
        accL1 = MFMA16F(A1l[kc], Bh[kc], accL1);
        accL1 = MFMA16F(A1h[kc], Bl[kc], accL1);
      }
      int n0 = (wv*8+ct)*16;
      float bb = bias1[ct];
      #pragma unroll
      for (int r=0;r<4;r++){
        hh[(kg*4+r)*HS + n0 + cn]    = (_Float16)leaky(acc0[r] + accL0[r]*LO_DESCALE + bb);
        hh[(16+kg*4+r)*HS + n0 + cn] = (_Float16)leaky(acc1[r] + accL1[r]*LO_DESCALE + bb);
      }
      #pragma unroll
      for (int kc=0;kc<6;kc++){ Bh[kc]=Bh2[kc]; Bl[kc]=Bl2[kc]; }
    }
  }
  __syncthreads();

  {
    f32x4 acc[3][2], accL[3][2];
    #pragma unroll
    for (int c=0;c<3;c++){
      #pragma unroll
      for (int g=0;g<2;g++){
        acc[c][g]  = (f32x4){0.f,0.f,0.f,0.f};
        accL[c][g] = (f32x4){0.f,0.f,0.f,0.f};
      }
    }
    f16x8 B2h[3], B2l[3];
    #pragma unroll
    for (int c=0;c<3;c++){
      size_t off = ((size_t)((wv*3+c)*16) << 9) + ln*8;
      B2h[c] = *(const f16x8*)(W2h + off);
      B2l[c] = *(const f16x8*)(W2l + off);
    }
    #pragma unroll 1
    for (int kc=0;kc<16;kc++){
      f16x8 N2h[3], N2l[3];
      if (kc < 15){
        #pragma unroll
        for (int c=0;c<3;c++){
          size_t off = ((size_t)((wv*3+c)*16 + kc + 1) << 9) + ln*8;
          N2h[c] = *(const f16x8*)(W2h + off);
          N2l[c] = *(const f16x8*)(W2l + off);
        }
      }
      int k0 = kc*32 + kg*8;
      f16x8 a0 = *(const f16x8*)&hh[cn*HS + k0];
      f16x8 a1 = *(const f16x8*)&hh[(16+cn)*HS + k0];
      #pragma unroll
      for (int c=0;c<3;c++){
        acc[c][0]  = MFMA16F(a0, B2h[c], acc[c][0]);
        accL[c][0] = MFMA16F(a0, B2l[c], accL[c][0]);
        acc[c][1]  = MFMA16F(a1, B2h[c], acc[c][1]);
        accL[c][1] = MFMA16F(a1, B2l[c], accL[c][1]);
      }
      #pragma unroll
      for (int c=0;c<3;c++){ B2h[c]=N2h[c]; B2l[c]=N2l[c]; }
    }
    #pragma unroll
    for (int c=0;c<3;c++){
      int n0 = (wv*3+c)*16;
      float bb = b2[n0 + cn];
      #pragma unroll
      for (int r=0;r<4;r++){
        int m0 = kg*4 + r, m1 = 16 + kg*4 + r;
        float res0 = (float)xh[m0*XS + n0 + cn] + (float)xl[m0*XS + n0 + cn]*LO_DESCALE;
        float res1 = (float)xh[m1*XS + n0 + cn] + (float)xl[m1*XS + n0 + cn]*LO_DESCALE;
        int ia = i0 + m0, ib = i0 + m1;
        if (ia < n) out[(size_t)ia*DD + n0 + cn] = leaky(res0 + acc[c][0][r] + accL[c][0][r]*LO_DESCALE + bb);
        if (ib < n) out[(size_t)ib*DD + n0 + cn] = leaky(res1 + acc[c][1][r] + accL[c][1][r]*LO_DESCALE + bb);
      }
    }
  }
}

// ============ MFMA prediction head with fused CrossNet ====================
constexpr int ZS = 392;

__global__ __launch_bounds__(256,3)
void k_pred_mfma(const float* __restrict__ deep, const float* __restrict__ X0,
                 const float* __restrict__ cw, const float* __restrict__ cb,
                 const _Float16* __restrict__ Wh, const _Float16* __restrict__ Wl,
                 const float* __restrict__ b1,
                 const float* __restrict__ w2, const float* __restrict__ b2,
                 float* __restrict__ y, int n)
{
  __shared__ __align__(16) _Float16 zh[32*ZS];
  __shared__ __align__(16) _Float16 zl[32*ZS];
  __shared__ float sred[4][32];
  int i0 = blockIdx.x*32;
  for (int idx = threadIdx.x; idx < 32*DD; idx += 256){
    int t = idx / DD, k = idx - t*DD;
    int i = i0 + t;
    float v = (i < n) ? deep[(size_t)i*DD + k] : 0.f;
    v *= Z_SCALE;
    _Float16 h = (_Float16)v;
    zh[t*ZS + k] = h;
    zl[t*ZS + k] = (_Float16)((v - (float)h)*LO_SCALE);
  }
  int wv = threadIdx.x >> 6, ln = threadIdx.x & 63;
  for (int m = 0; m < 8; m++){
    int t = wv*8 + m;
    int node = i0 + t;
    float v0[3], xc[3];
    if (node < n){
      const float* xr = X0 + (size_t)node*DD;
      #pragma unroll
      for (int q=0;q<3;q++){ v0[q] = xr[ln + 64*q]; xc[q] = v0[q]; }
      #pragma unroll
      for (int l=0;l<2;l++){
        float p = 0.f;
        #pragma unroll
        for (int q=0;q<3;q++) p += xc[q]*cw[l*DD + ln + 64*q];
        #pragma unroll
        for (int off=32; off>0; off>>=1) p += __shfl_xor(p, off, 64);
        #pragma unroll
        for (int q=0;q<3;q++) xc[q] = v0[q]*p + cb[l*DD + ln + 64*q] + xc[q];
      }
    } else {
      #pragma unroll
      for (int q=0;q<3;q++) xc[q] = 0.f;
    }
    #pragma unroll
    for (int q=0;q<3;q++){
      float v = xc[q]*Z_SCALE;
      _Float16 h = (_Float16)v;
      zh[t*ZS + DD + ln + 64*q] = h;
      zl[t*ZS + DD + ln + 64*q] = (_Float16)((v - (float)h)*LO_SCALE);
    }
  }
  __syncthreads();
  int cn = ln & 15, kg = ln >> 4;
  float vs0[4] = {0.f,0.f,0.f,0.f};
  float vs1[4] = {0.f,0.f,0.f,0.f};
  #pragma unroll 1
  for (int ct = 0; ct < 5; ct++){
    int nt = wv*5 + ct;
    int n0 = nt*16;
    f32x4 acc0 = {0.f,0.f,0.f,0.f}, accL0 = {0.f,0.f,0.f,0.f};
    f32x4 acc1 = {0.f,0.f,0.f,0.f}, accL1 = {0.f,0.f,0.f,0.f};
    const _Float16* wbh = Wh + ((size_t)nt*12 << 9) + ln*8;
    const _Float16* wbl = Wl + ((size_t)nt*12 << 9) + ln*8;
    #pragma unroll 4
    for (int kc = 0; kc < 12; kc++){
      f16x8 bh = *(const f16x8*)(wbh + (kc << 9));
      f16x8 bl = *(const f16x8*)(wbl + (kc << 9));
      int k0 = kc*32 + kg*8;
      f16x8 a0h = *(const f16x8*)&zh[cn*ZS + k0];
      f16x8 a0l = *(const f16x8*)&zl[cn*ZS + k0];
      f16x8 a1h = *(const f16x8*)&zh[(16+cn)*ZS + k0];
      f16x8 a1l = *(const f16x8*)&zl[(16+cn)*ZS + k0];
      acc0  = MFMA16F(a0h, bh, acc0);
      accL0 = MFMA16F(a0l, bh, accL0);
      accL0 = MFMA16F(a0h, bl, accL0);
      acc1  = MFMA16F(a1h, bh, acc1);
      accL1 = MFMA16F(a1l, bh, accL1);
      accL1 = MFMA16F(a1h, bl, accL1);
    }
    float bb = b1[n0 + cn];
    float ww = w2[n0 + cn];
    #pragma unroll
    for (int r=0;r<4;r++){
      float v0 = (acc0[r] + accL0[r]*LO_DESCALE)*Z_DESCALE + bb;
      float v1 = (acc1[r] + accL1[r]*LO_DESCALE)*Z_DESCALE + bb;
      vs0[r] += leaky(v0)*ww;
      vs1[r] += leaky(v1)*ww;
    }
  }
  #pragma unroll
  for (int r=0;r<4;r++){
    #pragma unroll
    for (int off=1; off<16; off<<=1){
      vs0[r] += __shfl_xor(vs0[r], off, 64);
      vs1[r] += __shfl_xor(vs1[r], off, 64);
    }
  }
  if (cn == 0){
    #pragma unroll
    for (int r=0;r<4;r++){
      sred[wv][kg*4 + r]      = vs0[r];
      sred[wv][16 + kg*4 + r] = vs1[r];
    }
  }
  __syncthreads();
  if (threadIdx.x < 32){
    int m = threadIdx.x;
    float s = sred[0][m] + sred[1][m] + sred[2][m] + sred[3][m] + b2[0];
    int i = i0 + m;
    if (i < n) y[i] = 1.f/(1.f + expf(-s));
  }
}

extern "C" void kernel_launch(void* const* d_in, const int* in_sizes, int n_in,
                              void* d_out, int out_size, void* d_ws, size_t ws_size,
                              hipStream_t stream)
{
  const int*   dx      = (const int*)d_in[0];
  const int*   ei      = (const int*)d_in[1];
  const float* w_g0    = (const float*)d_in[2];
  const float* b_g0    = (const float*)d_in[3];
  const float* w_gcn1  = (const float*)d_in[4];
  const float* b_gcn1  = (const float*)d_in[5];
  const float* w_gcn2  = (const float*)d_in[6];
  const float* b_gcn2  = (const float*)d_in[7];
  const float* res_w1  = (const float*)d_in[8];
  const float* res_b1  = (const float*)d_in[9];
  const float* res_w2  = (const float*)d_in[10];
  const float* res_b2  = (const float*)d_in[11];
  const float* cross_w = (const float*)d_in[12];
  const float* cross_b = (const float*)d_in[13];
  const float* p_w1    = (const float*)d_in[14];
  const float* p_b1    = (const float*)d_in[15];
  const float* p_w2    = (const float*)d_in[16];
  const float* p_b2    = (const float*)d_in[17];
  float* y = (float*)d_out;

  int n = in_sizes[0] / NCOLS;
  int E = in_sizes[1] / 2;
  const int* row = ei;
  const int* col = ei + E;

  float* ws  = (float*)d_ws;
  float* A   = ws;                         // [n,192] x0
  float* B   = A  + (size_t)192*n;         // [n,192] x_deep
  float* G   = B  + (size_t)192*n;         // [n,256] graph ping/pong
  float* E1  = G;                          // [n,128]
  float* E2v = G  + (size_t)128*n;         // [n,128]
  float* dinv= G  + (size_t)256*n;         // [n]
  int*  cnt    = (int*)(dinv + n);         // [n]
  int*  base   = cnt + n;                  // [n+2]
  int*  cursor = base + n + 2;             // [n]
  int*  bsum   = cursor + n;               // [256]
  int2* ebin   = (int2*)((((uintptr_t)(bsum + 256)) + 15) & ~(uintptr_t)15); // [E]
  _Float16* wt1h = (_Float16*)((((uintptr_t)(ebin + E)) + 15) & ~(uintptr_t)15);
  _Float16* wt1l = wt1h + (size_t)2*RES_HID*DD;
  _Float16* wt2h = wt1l + (size_t)2*RES_HID*DD;
  _Float16* wt2l = wt2h + (size_t)2*RES_HID*DD;
  _Float16* wph  = wt2l + (size_t)2*RES_HID*DD;
  _Float16* wpl  = wph  + (size_t)PRED_HID*2*DD;
  _Float16* wg0h = wpl  + (size_t)PRED_HID*2*DD;
  _Float16* wg0l = wg0h + (size_t)NH*EMB;
  _Float16* wg1h = wg0l + (size_t)NH*EMB;
  _Float16* wg1l = wg1h + (size_t)EMB*EMB;
  _Float16* wg2h = wg1l + (size_t)EMB*EMB;
  _Float16* wg2l = wg2h + (size_t)EMB*EMB;

  dim3 blk(256);
  int nb = (n + 255)/256;

  // --- cnt init, then merged weight-prep + histogram (1 launch) ---
  hipMemsetAsync(cnt, 0, (size_t)n*sizeof(int), stream);
  {
    int total = 4*DD*RES_HID + 2*DD*PRED_HID + NH*EMB + 2*EMB*EMB;
    k_wprep_hist<<<(total + E + 255)/256, blk, 0, stream>>>(
        res_w1, res_w2, p_w1, w_g0, w_gcn1, w_gcn2,
        wt1h, wt1l, wt2h, wt2l, wph, wpl,
        wg0h, wg0l, wg1h, wg1l, wg2h, wg2l,
        col, cnt, E);
  }

  // --- CSR scans + fill ---
  k_scanA<<<nb, blk, 0, stream>>>(cnt, bsum, n);
  k_scanB<<<1, blk, 0, stream>>>(bsum, nb);
  k_scanC<<<nb, blk, 0, stream>>>(cnt, bsum, base, cursor, dinv, n, E);
  k_fill <<<(E+255)/256, blk, 0, stream>>>(row, col, dinv, cursor, ebin, E);

  // --- node features ---
  int rbt = (n + 31)/32;
  k_embed_lin<<<rbt, blk, 0, stream>>>(dx, wg0h, wg0l, b_g0, A, E1, n);
  k_lin_mfma2<4><<<rbt, blk, 0, stream>>>(E1, EMB, wg1h, wg1l, nullptr, E2v, EMB, 0, n, 0);
  k_gather  <<<(n+1)/2, blk, 0, stream>>>(E2v, dinv, base, ebin, b_gcn1, E1, EMB, 0, n);
  k_lin_mfma2<4><<<rbt, blk, 0, stream>>>(E1, EMB, wg2h, wg2l, nullptr, E2v, EMB, 0, n, 0);
  k_gather  <<<(n+1)/2, blk, 0, stream>>>(E2v, dinv, base, ebin, b_gcn2, A, DD, NH, n);
  // --- ResDNN (r10 fused MFMA) ---
  k_resblock_mfma<<<rbt, blk, 0, stream>>>(A, wt1h, wt1l, res_b1,
                                           wt2h, wt2l, res_b2, B, n);
  k_resblock_mfma<<<rbt, blk, 0, stream>>>(B, wt1h + (size_t)DD*RES_HID, wt1l + (size_t)DD*RES_HID,
                                           res_b1 + RES_HID,
                                           wt2h + (size_t)DD*RES_HID, wt2l + (size_t)DD*RES_HID,
                                           res_b2 + DD, B, n);
  // --- prediction head (MFMA, fused CrossNet) ---
  k_pred_mfma<<<rbt, blk, 0, stream>>>(B, A, cross_w, cross_b, wph, wpl, p_b1, p_w2, p_b2, y, n);
}

// Round 16
// 608.652 us; speedup vs baseline: 1.0206x; 1.0206x over previous
//
#include <hip/hip_runtime.h>
#include <math.h>

constexpr int NCOLS   = 70;
constexpr int NH      = 64;
constexpr int EMB     = 128;
constexpr int DD      = 192;
constexpr int RES_HID = 512;
constexpr int PRED_HID= 320;

typedef _Float16 f16x8 __attribute__((ext_vector_type(8)));
typedef float    f32x4 __attribute__((ext_vector_type(4)));
#define MFMA16F(a,b,c) __builtin_amdgcn_mfma_f32_16x16x32_f16((a),(b),(c),0,0,0)

constexpr float LO_SCALE   = 4096.0f;
constexpr float LO_DESCALE = 1.0f/4096.0f;
constexpr float Z_SCALE    = 0.0625f;
constexpr float Z_DESCALE  = 16.0f;

__device__ __forceinline__ float leaky(float x){ return x > 0.f ? x : 0.01f*x; }

// ===================== CSR build for GCN aggregation ======================
__global__ void k_scanA(const int* __restrict__ cnt, int* __restrict__ bsum, int n){
  __shared__ int s;
  if (threadIdx.x == 0) s = 0;
  __syncthreads();
  int i = blockIdx.x*256 + threadIdx.x;
  int v = (i < n) ? cnt[i] : 0;
  #pragma unroll
  for (int o=32;o;o>>=1) v += __shfl_xor(v, o, 64);
  if ((threadIdx.x & 63) == 0) atomicAdd(&s, v);
  __syncthreads();
  if (threadIdx.x == 0) bsum[blockIdx.x] = s;
}
__global__ void k_scanB(int* bsum, int nb){
  __shared__ int s[256];
  __shared__ int carry;
  if (threadIdx.x == 0) carry = 0;
  __syncthreads();
  for (int start = 0; start < nb; start += 256){
    int i = start + threadIdx.x;
    int v = (i < nb) ? bsum[i] : 0;
    s[threadIdx.x] = v; __syncthreads();
    for (int o=1;o<256;o<<=1){
      int t = (threadIdx.x >= o) ? s[threadIdx.x-o] : 0;
      __syncthreads();
      s[threadIdx.x] += t; __syncthreads();
    }
    if (i < nb) bsum[i] = carry + s[threadIdx.x] - v;
    __syncthreads();
    if (threadIdx.x == 255) carry += s[255];
    __syncthreads();
  }
}
__global__ void k_scanC(const int* __restrict__ cnt, const int* __restrict__ bsum,
                        int* __restrict__ base, int* __restrict__ cursor,
                        float* __restrict__ dinv, int n, int E){
  __shared__ int s[256];
  int i = blockIdx.x*256 + threadIdx.x;
  int v = (i < n) ? cnt[i] : 0;
  s[threadIdx.x] = v; __syncthreads();
  for (int o=1;o<256;o<<=1){
    int t = (threadIdx.x >= o) ? s[threadIdx.x-o] : 0;
    __syncthreads();
    s[threadIdx.x] += t; __syncthreads();
  }
  if (i < n){
    int b = bsum[blockIdx.x] + s[threadIdx.x] - v;
    base[i] = b; cursor[i] = b;
    dinv[i] = rsqrtf((float)(v + 1));
  }
  if (i == n-1) base[n] = E;
}
__global__ void k_fill(const int* __restrict__ row, const int* __restrict__ col,
                       const float* __restrict__ dinv, int* __restrict__ cursor,
                       int2* __restrict__ ebin, int E){
  int e = blockIdx.x*256 + threadIdx.x;
  if (e < E){
    int r = row[e], c = col[e];
    int slot = atomicAdd(&cursor[c], 1);
    ebin[slot] = make_int2(r, __float_as_int(dinv[r]));
  }
}

// ===== weight prep v2 (coalesced fragment writes) + histogram, 1 launch ===
// Each thread builds one 8-half fragment: 16B vector stores, wave-contiguous.
__device__ __forceinline__ void pack_grp(const float* __restrict__ W,
                                         _Float16* __restrict__ Wh, _Float16* __restrict__ Wl,
                                         int K, int N, int g){
  int lane = g & 63;
  int blk  = g >> 6;             // nt*(K/32) + kc
  int KC = K >> 5;
  int nt = blk / KC, kc = blk - nt*KC;
  int nn = (nt << 4) | (lane & 15);
  int kbase = kc*32 + ((lane >> 4) << 3);
  f16x8 vh, vl;
  #pragma unroll
  for (int j=0;j<8;j++){
    float v = W[(size_t)(kbase + j)*N + nn];
    _Float16 h = (_Float16)v;
    vh[j] = h;
    vl[j] = (_Float16)((v - (float)h)*LO_SCALE);
  }
  size_t dst = ((size_t)blk << 9) + lane*8;
  *(f16x8*)(Wh + dst) = vh;
  *(f16x8*)(Wl + dst) = vl;
}
__global__ void k_wprep_hist(const float* res_w1, const float* res_w2, const float* p_w1,
                             const float* w_g0, const float* w_gcn1, const float* w_gcn2,
                             _Float16* wt1h, _Float16* wt1l, _Float16* wt2h, _Float16* wt2l,
                             _Float16* wph, _Float16* wpl, _Float16* wg0h, _Float16* wg0l,
                             _Float16* wg1h, _Float16* wg1l, _Float16* wg2h, _Float16* wg2l,
                             const int* __restrict__ col, int* __restrict__ cnt, int E)
{
  int idx = blockIdx.x*256 + threadIdx.x;
  constexpr int SG = DD*RES_HID/8;     // 12288 fragments per resblock W
  constexpr int PG = 2*DD*PRED_HID/8;  // 15360
  constexpr int G0 = NH*EMB/8;         // 1024
  constexpr int G1 = EMB*EMB/8;        // 2048
  constexpr int TOT = 4*SG + PG + G0 + 2*G1;
  constexpr int SZ = DD*RES_HID;
  if (idx < SG)                      pack_grp(res_w1,      wt1h,      wt1l,      DD, RES_HID, idx);
  else if (idx < 2*SG)               pack_grp(res_w1 + SZ, wt1h + SZ, wt1l + SZ, DD, RES_HID, idx - SG);
  else if (idx < 3*SG)               pack_grp(res_w2,      wt2h,      wt2l,      RES_HID, DD, idx - 2*SG);
  else if (idx < 4*SG)               pack_grp(res_w2 + SZ, wt2h + SZ, wt2l + SZ, RES_HID, DD, idx - 3*SG);
  else if (idx < 4*SG + PG)          pack_grp(p_w1,        wph,       wpl,       2*DD, PRED_HID, idx - 4*SG);
  else if (idx < 4*SG + PG + G0)     pack_grp(w_g0,        wg0h,      wg0l,      NH, EMB, idx - 4*SG - PG);
  else if (idx < 4*SG + PG + G0 + G1)pack_grp(w_gcn1,      wg1h,      wg1l,      EMB, EMB, idx - 4*SG - PG - G0);
  else if (idx < TOT)                pack_grp(w_gcn2,      wg2h,      wg2l,      EMB, EMB, idx - 4*SG - PG - G0 - G1);
  else if (idx < TOT + E)            atomicAdd(&cnt[col[idx - TOT]], 1);
}

// ======= fused embed + first linear (r13-proven) ==========================
__global__ __launch_bounds__(256,3)
void k_embed_lin(const int* __restrict__ dx,
                 const _Float16* __restrict__ Wh, const _Float16* __restrict__ Wl,
                 const float* __restrict__ bias,
                 float* __restrict__ A, float* __restrict__ out, int n)
{
  constexpr int KS = 68;
  __shared__ __align__(16) _Float16 xh[32*KS];
  int i0 = blockIdx.x*32;
  for (int idx = threadIdx.x; idx < 32*NH; idx += 256){
    int t = idx >> 6, k = idx & 63;
    int i = i0 + t;
    float v = (i < n) ? (float)dx[(size_t)i*NCOLS + k] : 0.f;
    if (i < n) A[(size_t)i*DD + k] = v;
    xh[t*KS + k] = (_Float16)v;
  }
  __syncthreads();
  int wv = threadIdx.x >> 6, ln = threadIdx.x & 63;
  int cn = ln & 15, kg = ln >> 4;
  f16x8 A0h[2], A1h[2];
  #pragma unroll
  for (int kc=0;kc<2;kc++){
    int k0 = kc*32 + kg*8;
    A0h[kc] = *(const f16x8*)&xh[cn*KS + k0];
    A1h[kc] = *(const f16x8*)&xh[(16+cn)*KS + k0];
  }
  #pragma unroll
  for (int t=0;t<2;t++){
    int nt = wv*2 + t, n0 = nt*16;
    const _Float16* wbh = Wh + (((size_t)nt*2) << 9) + ln*8;
    const _Float16* wbl = Wl + (((size_t)nt*2) << 9) + ln*8;
    f32x4 acc0={0.f,0.f,0.f,0.f}, accL0={0.f,0.f,0.f,0.f};
    f32x4 acc1={0.f,0.f,0.f,0.f}, accL1={0.f,0.f,0.f,0.f};
    #pragma unroll
    for (int kc=0;kc<2;kc++){
      f16x8 bh = *(const f16x8*)(wbh + ((size_t)kc<<9));
      f16x8 bl = *(const f16x8*)(wbl + ((size_t)kc<<9));
      acc0  = MFMA16F(A0h[kc], bh, acc0);
      accL0 = MFMA16F(A0h[kc], bl, accL0);
      acc1  = MFMA16F(A1h[kc], bh, acc1);
      accL1 = MFMA16F(A1h[kc], bl, accL1);
    }
    float bb = bias[n0 + cn];
    #pragma unroll
    for (int r=0;r<4;r++){
      int ia = i0 + kg*4 + r, ib = ia + 16;
      float v0 = leaky(acc0[r] + accL0[r]*LO_DESCALE + bb);
      float v1 = leaky(acc1[r] + accL1[r]*LO_DESCALE + bb);
      if (ia < n) out[(size_t)ia*EMB + n0 + cn] = v0;
      if (ib < n) out[(size_t)ib*EMB + n0 + cn] = v1;
    }
  }
}

// ============ MFMA dense layer, J=128, LDS-staged A =======================
template<int KC>
__global__ __launch_bounds__(256,3)
void k_lin_mfma2(const float* __restrict__ X, int ldx,
                 const _Float16* __restrict__ Wh, const _Float16* __restrict__ Wl,
                 const float* __restrict__ bias,
                 float* __restrict__ out, int ldo, int ooff, int n, int act)
{
  constexpr int K  = KC*32;
  constexpr int KS = K + 4;
  __shared__ __align__(16) _Float16 xh[32*KS];
  __shared__ __align__(16) _Float16 xl[32*KS];
  int i0 = blockIdx.x*32;
  for (int idx = threadIdx.x; idx < 32*K; idx += 256){
    int t = idx / K, k = idx - t*K;
    int i = i0 + t;
    float v = (i < n) ? X[(size_t)i*ldx + k] : 0.f;
    _Float16 h = (_Float16)v;
    xh[t*KS + k] = h;
    xl[t*KS + k] = (_Float16)((v - (float)h)*LO_SCALE);
  }
  __syncthreads();
  int wv = threadIdx.x >> 6, ln = threadIdx.x & 63;
  int cn = ln & 15, kg = ln >> 4;
  f16x8 A0h[KC], A0l[KC], A1h[KC], A1l[KC];
  #pragma unroll
  for (int kc=0;kc<KC;kc++){
    int k0 = kc*32 + kg*8;
    A0h[kc] = *(const f16x8*)&xh[cn*KS + k0];
    A0l[kc] = *(const f16x8*)&xl[cn*KS + k0];
    A1h[kc] = *(const f16x8*)&xh[(16+cn)*KS + k0];
    A1l[kc] = *(const f16x8*)&xl[(16+cn)*KS + k0];
  }
  #pragma unroll
  for (int t=0;t<2;t++){
    int nt = wv*2 + t, n0 = nt*16;
    const _Float16* wbh = Wh + (((size_t)nt*KC) << 9) + ln*8;
    const _Float16* wbl = Wl + (((size_t)nt*KC) << 9) + ln*8;
    f32x4 acc0={0.f,0.f,0.f,0.f}, accL0={0.f,0.f,0.f,0.f};
    f32x4 acc1={0.f,0.f,0.f,0.f}, accL1={0.f,0.f,0.f,0.f};
    #pragma unroll
    for (int kc=0;kc<KC;kc++){
      f16x8 bh = *(const f16x8*)(wbh + ((size_t)kc<<9));
      f16x8 bl = *(const f16x8*)(wbl + ((size_t)kc<<9));
      acc0  = MFMA16F(A0h[kc], bh, acc0);
      accL0 = MFMA16F(A0l[kc], bh, accL0);
      accL0 = MFMA16F(A0h[kc], bl, accL0);
      acc1  = MFMA16F(A1h[kc], bh, acc1);
      accL1 = MFMA16F(A1l[kc], bh, accL1);
      accL1 = MFMA16F(A1h[kc], bl, accL1);
    }
    float bb = bias ? bias[n0 + cn] : 0.f;
    #pragma unroll
    for (int r=0;r<4;r++){
      int ia = i0 + kg*4 + r, ib = ia + 16;
      float v0 = acc0[r] + accL0[r]*LO_DESCALE + bb;
      float v1 = acc1[r] + accL1[r]*LO_DESCALE + bb;
      if (act){ v0 = leaky(v0); v1 = leaky(v1); }
      if (ia < n) out[(size_t)ia*ldo + ooff + n0 + cn] = v0;
      if (ib < n) out[(size_t)ib*ldo + ooff + n0 + cn] = v1;
    }
  }
}

// ===================== GCN gather (r13-proven): float4 half-wave ==========
__global__ void k_gather(const float* __restrict__ h, const float* __restrict__ dinv,
                         const int* __restrict__ base, const int2* __restrict__ ebin,
                         const float* __restrict__ bias, float* __restrict__ out,
                         int ldo, int ooff, int n)
{
  int node = blockIdx.x*4 + (threadIdx.x >> 6);
  int lane = threadIdx.x & 63;
  if (node >= n) return;
  int half = lane >> 5, l32 = lane & 31;
  int b0 = base[node], b1 = base[node+1];
  float dc = dinv[node];
  float4 acc = {0.f,0.f,0.f,0.f};
  for (int e = b0 + half; e < b1; e += 2){
    int2 ee = ebin[e];
    float4 hv = ((const float4*)(h + (size_t)ee.x*EMB))[l32];
    float dd = __int_as_float(ee.y);
    acc.x = fmaf(hv.x, dd, acc.x);
    acc.y = fmaf(hv.y, dd, acc.y);
    acc.z = fmaf(hv.z, dd, acc.z);
    acc.w = fmaf(hv.w, dd, acc.w);
  }
  acc.x += __shfl_xor(acc.x, 32, 64);
  acc.y += __shfl_xor(acc.y, 32, 64);
  acc.z += __shfl_xor(acc.z, 32, 64);
  acc.w += __shfl_xor(acc.w, 32, 64);
  float4 hc = ((const float4*)(h + (size_t)node*EMB))[l32];
  float4 bv = ((const float4*)bias)[l32];
  float4 res;
  res.x = leaky((acc.x + hc.x*dc)*dc + bv.x);
  res.y = leaky((acc.y + hc.y*dc)*dc + bv.y);
  res.z = leaky((acc.z + hc.z*dc)*dc + bv.z);
  res.w = leaky((acc.w + hc.w*dc)*dc + bv.w);
  if (half == 0)
    *(float4*)(out + (size_t)node*ldo + ooff + 4*l32) = res;
}

// ===================== fused MFMA residual bottleneck (r10/r13 proven) ====
constexpr int XS = 196;
constexpr int HS = 516;

__global__ __launch_bounds__(256,2)
void k_resblock_mfma(const float* __restrict__ X,
                     const _Float16* __restrict__ W1h, const _Float16* __restrict__ W1l,
                     const float* __restrict__ b1,
                     const _Float16* __restrict__ W2h, const _Float16* __restrict__ W2l,
                     const float* __restrict__ b2,
                     float* __restrict__ out, int n)
{
  __shared__ __align__(16) _Float16 xh[32*XS];
  __shared__ __align__(16) _Float16 xl[32*XS];
  __shared__ __align__(16) _Float16 hh[32*HS];
  int i0 = blockIdx.x*32;
  for (int idx = threadIdx.x; idx < 32*DD; idx += 256){
    int t = idx / DD, k = idx - t*DD;
    int i = i0 + t;
    float v = (i < n) ? X[(size_t)i*DD + k] : 0.f;
    _Float16 h = (_Float16)v;
    xh[t*XS + k] = h;
    xl[t*XS + k] = (_Float16)((v - (float)h)*LO_SCALE);
  }
  __syncthreads();
  int wv = threadIdx.x >> 6, ln = threadIdx.x & 63;
  int cn = ln & 15, kg = ln >> 4;

  {
    f16x8 A0h[6], A0l[6], A1h[6], A1l[6];
    #pragma unroll
    for (int kc=0;kc<6;kc++){
      int k0 = kc*32 + kg*8;
      A0h[kc] = *(const f16x8*)&xh[cn*XS + k0];
      A0l[kc] = *(const f16x8*)&xl[cn*XS + k0];
      A1h[kc] = *(const f16x8*)&xh[(16+cn)*XS + k0];
      A1l[kc] = *(const f16x8*)&xl[(16+cn)*XS + k0];
    }
    float bias1[8];
    #pragma unroll
    for (int ct=0;ct<8;ct++) bias1[ct] = b1[(wv*8+ct)*16 + cn];
    const _Float16* pbh = W1h + ((size_t)(wv*8)*6 << 9) + ln*8;
    const _Float16* pbl = W1l + ((size_t)(wv*8)*6 << 9) + ln*8;
    f16x8 Bh[6], Bl[6];
    #pragma unroll
    for (int kc=0;kc<6;kc++){
      Bh[kc] = *(const f16x8*)(pbh + ((size_t)kc<<9));
      Bl[kc] = *(const f16x8*)(pbl + ((size_t)kc<<9));
    }
    #pragma unroll 1
    for (int ct = 0; ct < 8; ct++){
      f16x8 Bh2[6], Bl2[6];
      if (ct < 7){
        const _Float16* nh = pbh + ((size_t)((ct+1)*6) << 9);
        const _Float16* nl = pbl + ((size_t)((ct+1)*6) << 9);
        #pragma unroll
        for (int kc=0;kc<6;kc++){
          Bh2[kc] = *(const f16x8*)(nh + ((size_t)kc<<9));
          Bl2[kc] = *(const f16x8*)(nl + ((size_t)kc<<9));
        }
      }
      f32x4 acc0={0.f,0.f,0.f,0.f}, accL0={0.f,0.f,0.f,0.f};
      f32x4 acc1={0.f,0.f,0.f,0.f}, accL1={0.f,0.f,0.f,0.f};
      #pragma unroll
      for (int kc=0;kc<6;kc++){
        acc0  = MFMA16F(A0h[kc], Bh[kc], acc0);
        accL0 = MFMA16F(A0l[kc], Bh[kc], accL0);
        accL0 = MFMA16F(A0h[kc], Bl[kc], accL0);
        acc1  = MFMA16F(A1h[kc], Bh[kc], acc1);
        accL1 = MFMA16F(A1l[kc], Bh[kc], accL1);
        accL1 = MFMA16F(A1h[kc], Bl[kc], accL1);
      }
      int n0 = (wv*8+ct)*16;
      float bb = bias1[ct];
      #pragma unroll
      for (int r=0;r<4;r++){
        hh[(kg*4+r)*HS + n0 + cn]    = (_Float16)leaky(acc0[r] + accL0[r]*LO_DESCALE + bb);
        hh[(16+kg*4+r)*HS + n0 + cn] = (_Float16)leaky(acc1[r] + accL1[r]*LO_DESCALE + bb);
      }
      #pragma unroll
      for (int kc=0;kc<6;kc++){ Bh[kc]=Bh2[kc]; Bl[kc]=Bl2[kc]; }
    }
  }
  __syncthreads();

  {
    f32x4 acc[3][2], accL[3][2];
    #pragma unroll
    for (int c=0;c<3;c++){
      #pragma unroll
      for (int g=0;g<2;g++){
        acc[c][g]  = (f32x4){0.f,0.f,0.f,0.f};
        accL[c][g] = (f32x4){0.f,0.f,0.f,0.f};
      }
    }
    f16x8 B2h[3], B2l[3];
    #pragma unroll
    for (int c=0;c<3;c++){
      size_t off = ((size_t)((wv*3+c)*16) << 9) + ln*8;
      B2h[c] = *(const f16x8*)(W2h + off);
      B2l[c] = *(const f16x8*)(W2l + off);
    }
    #pragma unroll 1
    for (int kc=0;kc<16;kc++){
      f16x8 N2h[3], N2l[3];
      if (kc < 15){
        #pragma unroll
        for (int c=0;c<3;c++){
          size_t off = ((size_t)((wv*3+c)*16 + kc + 1) << 9) + ln*8;
          N2h[c] = *(const f16x8*)(W2h + off);
          N2l[c] = *(const f16x8*)(W2l + off);
        }
      }
      int k0 = kc*32 + kg*8;
      f16x8 a0 = *(const f16x8*)&hh[cn*HS + k0];
      f16x8 a1 = *(const f16x8*)&hh[(16+cn)*HS + k0];
      #pragma unroll
      for (int c=0;c<3;c++){
        acc[c][0]  = MFMA16F(a0, B2h[c], acc[c][0]);
        accL[c][0] = MFMA16F(a0, B2l[c], accL[c][0]);
        acc[c][1]  = MFMA16F(a1, B2h[c], acc[c][1]);
        accL[c][1] = MFMA16F(a1, B2l[c], accL[c][1]);
      }
      #pragma unroll
      for (int c=0;c<3;c++){ B2h[c]=N2h[c]; B2l[c]=N2l[c]; }
    }
    #pragma unroll
    for (int c=0;c<3;c++){
      int n0 = (wv*3+c)*16;
      float bb = b2[n0 + cn];
      #pragma unroll
      for (int r=0;r<4;r++){
        int m0 = kg*4 + r, m1 = 16 + kg*4 + r;
        float res0 = (float)xh[m0*XS + n0 + cn] + (float)xl[m0*XS + n0 + cn]*LO_DESCALE;
        float res1 = (float)xh[m1*XS + n0 + cn] + (float)xl[m1*XS + n0 + cn]*LO_DESCALE;
        int ia = i0 + m0, ib = i0 + m1;
        if (ia < n) out[(size_t)ia*DD + n0 + cn] = leaky(res0 + acc[c][0][r] + accL[c][0][r]*LO_DESCALE + bb);
        if (ib < n) out[(size_t)ib*DD + n0 + cn] = leaky(res1 + acc[c][1][r] + accL[c][1][r]*LO_DESCALE + bb);
      }
    }
  }
}

// ============ MFMA prediction head with fused CrossNet ====================
constexpr int ZS = 392;

__global__ __launch_bounds__(256,3)
void k_pred_mfma(const float* __restrict__ deep, const float* __restrict__ X0,
                 const float* __restrict__ cw, const float* __restrict__ cb,
                 const _Float16* __restrict__ Wh, const _Float16* __restrict__ Wl,
                 const float* __restrict__ b1,
                 const float* __restrict__ w2, const float* __restrict__ b2,
                 float* __restrict__ y, int n)
{
  __shared__ __align__(16) _Float16 zh[32*ZS];
  __shared__ __align__(16) _Float16 zl[32*ZS];
  __shared__ float sred[4][32];
  int i0 = blockIdx.x*32;
  for (int idx = threadIdx.x; idx < 32*DD; idx += 256){
    int t = idx / DD, k = idx - t*DD;
    int i = i0 + t;
    float v = (i < n) ? deep[(size_t)i*DD + k] : 0.f;
    v *= Z_SCALE;
    _Float16 h = (_Float16)v;
    zh[t*ZS + k] = h;
    zl[t*ZS + k] = (_Float16)((v - (float)h)*LO_SCALE);
  }
  int wv = threadIdx.x >> 6, ln = threadIdx.x & 63;
  for (int m = 0; m < 8; m++){
    int t = wv*8 + m;
    int node = i0 + t;
    float v0[3], xc[3];
    if (node < n){
      const float* xr = X0 + (size_t)node*DD;
      #pragma unroll
      for (int q=0;q<3;q++){ v0[q] = xr[ln + 64*q]; xc[q] = v0[q]; }
      #pragma unroll
      for (int l=0;l<2;l++){
        float p = 0.f;
        #pragma unroll
        for (int q=0;q<3;q++) p += xc[q]*cw[l*DD + ln + 64*q];
        #pragma unroll
        for (int off=32; off>0; off>>=1) p += __shfl_xor(p, off, 64);
        #pragma unroll
        for (int q=0;q<3;q++) xc[q] = v0[q]*p + cb[l*DD + ln + 64*q] + xc[q];
      }
    } else {
      #pragma unroll
      for (int q=0;q<3;q++) xc[q] = 0.f;
    }
    #pragma unroll
    for (int q=0;q<3;q++){
      float v = xc[q]*Z_SCALE;
      _Float16 h = (_Float16)v;
      zh[t*ZS + DD + ln + 64*q] = h;
      zl[t*ZS + DD + ln + 64*q] = (_Float16)((v - (float)h)*LO_SCALE);
    }
  }
  __syncthreads();
  int cn = ln & 15, kg = ln >> 4;
  float vs0[4] = {0.f,0.f,0.f,0.f};
  float vs1[4] = {0.f,0.f,0.f,0.f};
  #pragma unroll 1
  for (int ct = 0; ct < 5; ct++){
    int nt = wv*5 + ct;
    int n0 = nt*16;
    f32x4 acc0 = {0.f,0.f,0.f,0.f}, accL0 = {0.f,0.f,0.f,0.f};
    f32x4 acc1 = {0.f,0.f,0.f,0.f}, accL1 = {0.f,0.f,0.f,0.f};
    const _Float16* wbh = Wh + ((size_t)nt*12 << 9) + ln*8;
    const _Float16* wbl = Wl + ((size_t)nt*12 << 9) + ln*8;
    #pragma unroll 4
    for (int kc = 0; kc < 12; kc++){
      f16x8 bh = *(const f16x8*)(wbh + (kc << 9));
      f16x8 bl = *(const f16x8*)(wbl + (kc << 9));
      int k0 = kc*32 + kg*8;
      f16x8 a0h = *(const f16x8*)&zh[cn*ZS + k0];
      f16x8 a0l = *(const f16x8*)&zl[cn*ZS + k0];
      f16x8 a1h = *(const f16x8*)&zh[(16+cn)*ZS + k0];
      f16x8 a1l = *(const f16x8*)&zl[(16+cn)*ZS + k0];
      acc0  = MFMA16F(a0h, bh, acc0);
      accL0 = MFMA16F(a0l, bh, accL0);
      accL0 = MFMA16F(a0h, bl, accL0);
      acc1  = MFMA16F(a1h, bh, acc1);
      accL1 = MFMA16F(a1l, bh, accL1);
      accL1 = MFMA16F(a1h, bl, accL1);
    }
    float bb = b1[n0 + cn];
    float ww = w2[n0 + cn];
    #pragma unroll
    for (int r=0;r<4;r++){
      float v0 = (acc0[r] + accL0[r]*LO_DESCALE)*Z_DESCALE + bb;
      float v1 = (acc1[r] + accL1[r]*LO_DESCALE)*Z_DESCALE + bb;
      vs0[r] += leaky(v0)*ww;
      vs1[r] += leaky(v1)*ww;
    }
  }
  #pragma unroll
  for (int r=0;r<4;r++){
    #pragma unroll
    for (int off=1; off<16; off<<=1){
      vs0[r] += __shfl_xor(vs0[r], off, 64);
      vs1[r] += __shfl_xor(vs1[r], off, 64);
    }
  }
  if (cn == 0){
    #pragma unroll
    for (int r=0;r<4;r++){
      sred[wv][kg*4 + r]      = vs0[r];
      sred[wv][16 + kg*4 + r] = vs1[r];
    }
  }
  __syncthreads();
  if (threadIdx.x < 32){
    int m = threadIdx.x;
    float s = sred[0][m] + sred[1][m] + sred[2][m] + sred[3][m] + b2[0];
    int i = i0 + m;
    if (i < n) y[i] = 1.f/(1.f + expf(-s));
  }
}

extern "C" void kernel_launch(void* const* d_in, const int* in_sizes, int n_in,
                              void* d_out, int out_size, void* d_ws, size_t ws_size,
                              hipStream_t stream)
{
  const int*   dx      = (const int*)d_in[0];
  const int*   ei      = (const int*)d_in[1];
  const float* w_g0    = (const float*)d_in[2];
  const float* b_g0    = (const float*)d_in[3];
  const float* w_gcn1  = (const float*)d_in[4];
  const float* b_gcn1  = (const float*)d_in[5];
  const float* w_gcn2  = (const float*)d_in[6];
  const float* b_gcn2  = (const float*)d_in[7];
  const float* res_w1  = (const float*)d_in[8];
  const float* res_b1  = (const float*)d_in[9];
  const float* res_w2  = (const float*)d_in[10];
  const float* res_b2  = (const float*)d_in[11];
  const float* cross_w = (const float*)d_in[12];
  const float* cross_b = (const float*)d_in[13];
  const float* p_w1    = (const float*)d_in[14];
  const float* p_b1    = (const float*)d_in[15];
  const float* p_w2    = (const float*)d_in[16];
  const float* p_b2    = (const float*)d_in[17];
  float* y = (float*)d_out;

  int n = in_sizes[0] / NCOLS;
  int E = in_sizes[1] / 2;
  const int* row = ei;
  const int* col = ei + E;

  float* ws  = (float*)d_ws;
  float* A   = ws;                         // [n,192] x0
  float* B   = A  + (size_t)192*n;         // [n,192] x_deep
  float* G   = B  + (size_t)192*n;         // [n,256] graph ping/pong
  float* E1  = G;                          // [n,128]
  float* E2v = G  + (size_t)128*n;         // [n,128]
  float* dinv= G  + (size_t)256*n;         // [n]
  int*  cnt    = (int*)(dinv + n);         // [n]
  int*  base   = cnt + n;                  // [n+2]
  int*  cursor = base + n + 2;             // [n]
  int*  bsum   = cursor + n;               // [256]
  int2* ebin   = (int2*)((((uintptr_t)(bsum + 256)) + 15) & ~(uintptr_t)15); // [E]
  _Float16* wt1h = (_Float16*)((((uintptr_t)(ebin + E)) + 15) & ~(uintptr_t)15);
  _Float16* wt1l = wt1h + (size_t)2*RES_HID*DD;
  _Float16* wt2h = wt1l + (size_t)2*RES_HID*DD;
  _Float16* wt2l = wt2h + (size_t)2*RES_HID*DD;
  _Float16* wph  = wt2l + (size_t)2*RES_HID*DD;
  _Float16* wpl  = wph  + (size_t)PRED_HID*2*DD;
  _Float16* wg0h = wpl  + (size_t)PRED_HID*2*DD;
  _Float16* wg0l = wg0h + (size_t)NH*EMB;
  _Float16* wg1h = wg0l + (size_t)NH*EMB;
  _Float16* wg1l = wg1h + (size_t)EMB*EMB;
  _Float16* wg2h = wg1l + (size_t)EMB*EMB;
  _Float16* wg2l = wg2h + (size_t)EMB*EMB;

  dim3 blk(256);
  int nb = (n + 255)/256;

  // --- cnt init, then merged coalesced weight-prep + histogram ---
  hipMemsetAsync(cnt, 0, (size_t)n*sizeof(int), stream);
  {
    int totg = (4*DD*RES_HID + 2*DD*PRED_HID + NH*EMB + 2*EMB*EMB)/8;
    k_wprep_hist<<<(totg + E + 255)/256, blk, 0, stream>>>(
        res_w1, res_w2, p_w1, w_g0, w_gcn1, w_gcn2,
        wt1h, wt1l, wt2h, wt2l, wph, wpl,
        wg0h, wg0l, wg1h, wg1l, wg2h, wg2l,
        col, cnt, E);
  }

  // --- CSR scans + fill ---
  k_scanA<<<nb, blk, 0, stream>>>(cnt, bsum, n);
  k_scanB<<<1, blk, 0, stream>>>(bsum, nb);
  k_scanC<<<nb, blk, 0, stream>>>(cnt, bsum, base, cursor, dinv, n, E);
  k_fill <<<(E+255)/256, blk, 0, stream>>>(row, col, dinv, cursor, ebin, E);

  // --- node features ---
  int rbt = (n + 31)/32;
  k_embed_lin<<<rbt, blk, 0, stream>>>(dx, wg0h, wg0l, b_g0, A, E1, n);
  k_lin_mfma2<4><<<rbt, blk, 0, stream>>>(E1, EMB, wg1h, wg1l, nullptr, E2v, EMB, 0, n, 0);
  k_gather  <<<(n+3)/4, blk, 0, stream>>>(E2v, dinv, base, ebin, b_gcn1, E1, EMB, 0, n);
  k_lin_mfma2<4><<<rbt, blk, 0, stream>>>(E1, EMB, wg2h, wg2l, nullptr, E2v, EMB, 0, n, 0);
  k_gather  <<<(n+3)/4, blk, 0, stream>>>(E2v, dinv, base, ebin, b_gcn2, A, DD, NH, n);
  // --- ResDNN (r10 fused MFMA) ---
  k_resblock_mfma<<<rbt, blk, 0, stream>>>(A, wt1h, wt1l, res_b1,
                                           wt2h, wt2l, res_b2, B, n);
  k_resblock_mfma<<<rbt, blk, 0, stream>>>(B, wt1h + (size_t)DD*RES_HID, wt1l + (size_t)DD*RES_HID,
                                           res_b1 + RES_HID,
                                           wt2h + (size_t)DD*RES_HID, wt2l + (size_t)DD*RES_HID,
                                           res_b2 + DD, B, n);
  // --- prediction head (MFMA, fused CrossNet) ---
  k_pred_mfma<<<rbt, blk, 0, stream>>>(B, A, cross_w, cross_b, wph, wpl, p_b1, p_w2, p_b2, y, n);
}